// Round 5
// baseline (38.716 us; speedup 1.0000x reference)
//
#include <hip/hip_runtime.h>

#define DIM 32
#define H1 64
#define BLK 256
#define SPB 128          // samples per block: 2 threads cooperate per sample
#define RS 104           // LDS row stride in bf16 elems (208 B, 16B-aligned)

typedef __attribute__((ext_vector_type(8))) short bf16x8;
typedef __attribute__((ext_vector_type(4))) float f32x4;

__device__ __forceinline__ unsigned short f2bf(float f) {
    unsigned u = __float_as_uint(f);
    unsigned r = ((u >> 16) & 1u) + 0x7fffu;   // round-to-nearest-even
    return (unsigned short)((u + r) >> 16);
}

__global__ __launch_bounds__(BLK, 4) void mtn_fused(
    const int* __restrict__ uid, const int* __restrict__ iid,
    const float* __restrict__ Uw, const float* __restrict__ Qw,
    const float* __restrict__ Aw, const float* __restrict__ Bw,
    const float* __restrict__ W1, const float* __restrict__ b1g,
    const float* __restrict__ W2, const float* __restrict__ b2g,
    float* __restrict__ out, int batch)
{
    __shared__ unsigned short Xs[SPB][RS];   // 26.6 KB

    const int t    = threadIdx.x;
    const int srow = t >> 1;       // local sample row
    const int h    = t & 1;        // which half of the embedding this thread owns
    const int s    = blockIdx.x * SPB + srow;
    const bool valid = (s < batch);

    const int u_idx = valid ? uid[s] : 0;
    const int q_idx = valid ? iid[s] : 0;

    // half-row gathers: 4 float4 of u, 4 float4 of q per thread
    const float4* up = (const float4*)(Uw + (long long)u_idx * DIM + h * 16);
    const float4* qp = (const float4*)(Qw + (long long)q_idx * DIM + h * 16);
    float4 uv0 = up[0], uv1 = up[1], uv2 = up[2], uv3 = up[3];
    float4 qv0 = qp[0], qv1 = qp[1], qv2 = qp[2], qv3 = qp[3];
    float bias = h ? Bw[q_idx] : Aw[u_idx];

    // ---- W1 B-fragments straight from global (independent -> overlaps gathers)
    const int lane = t & 63;
    const int wave = t >> 6;
    const int lr = lane & 15;      // B column / C column
    const int lg = lane >> 4;      // k-group / C row-group

    bf16x8 bfrag[3][4];
#pragma unroll
    for (int ks = 0; ks < 3; ++ks)
#pragma unroll
        for (int n = 0; n < 4; ++n) {
            const float4* wp = (const float4*)(W1 + (n * 16 + lr) * 96 + ks * 32 + lg * 8);
            float4 w0 = wp[0], w1 = wp[1];
            bf16x8 f;
            f[0] = (short)f2bf(w0.x); f[1] = (short)f2bf(w0.y);
            f[2] = (short)f2bf(w0.z); f[3] = (short)f2bf(w0.w);
            f[4] = (short)f2bf(w1.x); f[5] = (short)f2bf(w1.y);
            f[6] = (short)f2bf(w1.z); f[7] = (short)f2bf(w1.w);
            bfrag[ks][n] = f;
        }
    float w2l[4], b1l[4];
#pragma unroll
    for (int n = 0; n < 4; ++n) {
        w2l[n] = W2[n * 16 + lr];
        b1l[n] = b1g[n * 16 + lr];
    }
    const float b2v = b2g[0];

    // ---- products, partial dot, stage x = [u|q|uq] halves as bf16 ----
    float dotp = bias;
    bf16x8 ubv[2], qbv[2], pbv[2];
    {
        const float ue[16] = {uv0.x,uv0.y,uv0.z,uv0.w, uv1.x,uv1.y,uv1.z,uv1.w,
                              uv2.x,uv2.y,uv2.z,uv2.w, uv3.x,uv3.y,uv3.z,uv3.w};
        const float qe[16] = {qv0.x,qv0.y,qv0.z,qv0.w, qv1.x,qv1.y,qv1.z,qv1.w,
                              qv2.x,qv2.y,qv2.z,qv2.w, qv3.x,qv3.y,qv3.z,qv3.w};
#pragma unroll
        for (int e = 0; e < 16; ++e) {
            float pp = ue[e] * qe[e];
            dotp += pp;
            ubv[e >> 3][e & 7] = (short)f2bf(ue[e]);
            qbv[e >> 3][e & 7] = (short)f2bf(qe[e]);
            pbv[e >> 3][e & 7] = (short)f2bf(pp);
        }
    }
    // pair (even,odd lanes) holds the two halves + (Aw, Bw) respectively
    dotp += __shfl_xor(dotp, 1);
    if (valid && h == 0) out[s] = dotp;

    *(bf16x8*)&Xs[srow][h * 16]          = ubv[0];
    *(bf16x8*)&Xs[srow][h * 16 + 8]      = ubv[1];
    *(bf16x8*)&Xs[srow][32 + h * 16]     = qbv[0];
    *(bf16x8*)&Xs[srow][32 + h * 16 + 8] = qbv[1];
    *(bf16x8*)&Xs[srow][64 + h * 16]     = pbv[0];
    *(bf16x8*)&Xs[srow][64 + h * 16 + 8] = pbv[1];

    __syncthreads();

    // ---- phase 2: MFMA MLP, each wave does 2 m-tiles of 16 samples ----
    const int sbase = blockIdx.x * SPB;
    for (int mm = 0; mm < 2; ++mm) {
        const int rowb = wave * 32 + mm * 16 + lr;
        bf16x8 a0 = *(const bf16x8*)&Xs[rowb][0 * 32 + lg * 8];
        bf16x8 a1 = *(const bf16x8*)&Xs[rowb][1 * 32 + lg * 8];
        bf16x8 a2 = *(const bf16x8*)&Xs[rowb][2 * 32 + lg * 8];

        f32x4 c0 = {b1l[0], b1l[0], b1l[0], b1l[0]};
        f32x4 c1 = {b1l[1], b1l[1], b1l[1], b1l[1]};
        f32x4 c2 = {b1l[2], b1l[2], b1l[2], b1l[2]};
        f32x4 c3 = {b1l[3], b1l[3], b1l[3], b1l[3]};

        c0 = __builtin_amdgcn_mfma_f32_16x16x32_bf16(a0, bfrag[0][0], c0, 0, 0, 0);
        c1 = __builtin_amdgcn_mfma_f32_16x16x32_bf16(a0, bfrag[0][1], c1, 0, 0, 0);
        c2 = __builtin_amdgcn_mfma_f32_16x16x32_bf16(a0, bfrag[0][2], c2, 0, 0, 0);
        c3 = __builtin_amdgcn_mfma_f32_16x16x32_bf16(a0, bfrag[0][3], c3, 0, 0, 0);
        c0 = __builtin_amdgcn_mfma_f32_16x16x32_bf16(a1, bfrag[1][0], c0, 0, 0, 0);
        c1 = __builtin_amdgcn_mfma_f32_16x16x32_bf16(a1, bfrag[1][1], c1, 0, 0, 0);
        c2 = __builtin_amdgcn_mfma_f32_16x16x32_bf16(a1, bfrag[1][2], c2, 0, 0, 0);
        c3 = __builtin_amdgcn_mfma_f32_16x16x32_bf16(a1, bfrag[1][3], c3, 0, 0, 0);
        c0 = __builtin_amdgcn_mfma_f32_16x16x32_bf16(a2, bfrag[2][0], c0, 0, 0, 0);
        c1 = __builtin_amdgcn_mfma_f32_16x16x32_bf16(a2, bfrag[2][1], c1, 0, 0, 0);
        c2 = __builtin_amdgcn_mfma_f32_16x16x32_bf16(a2, bfrag[2][2], c2, 0, 0, 0);
        c3 = __builtin_amdgcn_mfma_f32_16x16x32_bf16(a2, bfrag[2][3], c3, 0, 0, 0);

        float tot[4];
#pragma unroll
        for (int r = 0; r < 4; ++r) {
            float p = fmaxf(c0[r], 0.f) * w2l[0] + fmaxf(c1[r], 0.f) * w2l[1]
                    + fmaxf(c2[r], 0.f) * w2l[2] + fmaxf(c3[r], 0.f) * w2l[3];
            p += __shfl_xor(p, 1);
            p += __shfl_xor(p, 2);
            p += __shfl_xor(p, 4);
            p += __shfl_xor(p, 8);
            tot[r] = p;
        }
        if (lr < 4) {
            int so = sbase + wave * 32 + mm * 16 + lg * 4 + lr;
            if (so < batch) out[batch + so] = fmaxf(tot[lr] + b2v, 0.f);
        }
    }
}

extern "C" void kernel_launch(void* const* d_in, const int* in_sizes, int n_in,
                              void* d_out, int out_size, void* d_ws, size_t ws_size,
                              hipStream_t stream) {
    const int*   uid = (const int*)  d_in[0];
    const int*   iid = (const int*)  d_in[1];
    const float* Uw  = (const float*)d_in[2];
    const float* Qw  = (const float*)d_in[3];
    const float* Aw  = (const float*)d_in[4];
    const float* Bw  = (const float*)d_in[5];
    const float* W1  = (const float*)d_in[6];
    const float* b1  = (const float*)d_in[7];
    const float* W2  = (const float*)d_in[8];
    const float* b2  = (const float*)d_in[9];
    float* out = (float*)d_out;
    int batch = in_sizes[0];

    int blocks = (batch + SPB - 1) / SPB;
    hipLaunchKernelGGL(mtn_fused, dim3(blocks), dim3(BLK), 0, stream,
                       uid, iid, Uw, Qw, Aw, Bw, W1, b1, W2, b2, out, batch);
}

// Round 6
// 23.519 us; speedup vs baseline: 1.6461x; 1.6461x over previous
//
#include <hip/hip_runtime.h>

#define DIM 32
#define H1 64
#define BLK 256
#define SPB 128          // samples per block: 2 threads cooperate per sample
#define RS 104           // LDS row stride in bf16 elems (208 B, 16B-aligned)

typedef __attribute__((ext_vector_type(8))) short bf16x8;
typedef __attribute__((ext_vector_type(4))) float f32x4;

__device__ __forceinline__ unsigned short f2bf(float f) {
    unsigned u = __float_as_uint(f);
    unsigned r = ((u >> 16) & 1u) + 0x7fffu;   // round-to-nearest-even
    return (unsigned short)((u + r) >> 16);
}

// Pack W1 [64][96] into MFMA B-fragment order (bf16):
// Bpack[((ks*4+n)*64 + l)*8 + e] = bf16( W1[ n*16+(l&15) ][ ks*32 + (l>>4)*8 + e ] )
__global__ __launch_bounds__(256) void prep_pack(const float* __restrict__ W1,
                                                 unsigned short* __restrict__ Bpack) {
    for (int idx = threadIdx.x; idx < 3 * 4 * 64 * 8; idx += 256) {
        int e  = idx & 7;
        int l  = (idx >> 3) & 63;
        int n  = (idx >> 9) & 3;
        int ks = idx >> 11;
        int j = n * 16 + (l & 15);
        int k = ks * 32 + ((l >> 4) << 3) + e;
        Bpack[idx] = f2bf(W1[j * 96 + k]);
    }
}

__global__ __launch_bounds__(BLK, 4) void mtn_fused(
    const int* __restrict__ uid, const int* __restrict__ iid,
    const float* __restrict__ Uw, const float* __restrict__ Qw,
    const float* __restrict__ Aw, const float* __restrict__ Bw,
    const unsigned short* __restrict__ Bpack, const float* __restrict__ b1g,
    const float* __restrict__ W2, const float* __restrict__ b2g,
    float* __restrict__ out, int batch)
{
    __shared__ unsigned short Xs[SPB][RS];   // 26.6 KB

    const int t    = threadIdx.x;
    const int srow = t >> 1;       // local sample row
    const int h    = t & 1;        // which half of the embedding this thread owns
    const int s    = blockIdx.x * SPB + srow;
    const bool valid = (s < batch);

    const int u_idx = valid ? uid[s] : 0;
    const int q_idx = valid ? iid[s] : 0;

    // half-row gathers: 4 float4 of u, 4 float4 of q per thread (64 B each)
    const float4* up = (const float4*)(Uw + (long long)u_idx * DIM + h * 16);
    const float4* qp = (const float4*)(Qw + (long long)q_idx * DIM + h * 16);
    float4 uv0 = up[0], uv1 = up[1], uv2 = up[2], uv3 = up[3];
    float4 qv0 = qp[0], qv1 = qp[1], qv2 = qp[2], qv3 = qp[3];
    const float* bptr = h ? (Bw + q_idx) : (Aw + u_idx);
    float bias = *bptr;

    // ---- products, partial dot, stage x = [u|q|uq] halves as bf16 ----
    float dotp = bias;
    {
        bf16x8 ubv[2], qbv[2], pbv[2];
        const float ue[16] = {uv0.x,uv0.y,uv0.z,uv0.w, uv1.x,uv1.y,uv1.z,uv1.w,
                              uv2.x,uv2.y,uv2.z,uv2.w, uv3.x,uv3.y,uv3.z,uv3.w};
        const float qe[16] = {qv0.x,qv0.y,qv0.z,qv0.w, qv1.x,qv1.y,qv1.z,qv1.w,
                              qv2.x,qv2.y,qv2.z,qv2.w, qv3.x,qv3.y,qv3.z,qv3.w};
#pragma unroll
        for (int e = 0; e < 16; ++e) {
            float pp = ue[e] * qe[e];
            dotp += pp;
            ubv[e >> 3][e & 7] = (short)f2bf(ue[e]);
            qbv[e >> 3][e & 7] = (short)f2bf(qe[e]);
            pbv[e >> 3][e & 7] = (short)f2bf(pp);
        }
        *(bf16x8*)&Xs[srow][h * 16]          = ubv[0];
        *(bf16x8*)&Xs[srow][h * 16 + 8]      = ubv[1];
        *(bf16x8*)&Xs[srow][32 + h * 16]     = qbv[0];
        *(bf16x8*)&Xs[srow][32 + h * 16 + 8] = qbv[1];
        *(bf16x8*)&Xs[srow][64 + h * 16]     = pbv[0];
        *(bf16x8*)&Xs[srow][64 + h * 16 + 8] = pbv[1];
    }
    // pair (even,odd lanes) holds the two halves + (Aw, Bw) respectively
    dotp += __shfl_xor(dotp, 1);
    if (valid && h == 0) out[s] = dotp;

    __syncthreads();

    // ---- phase 2: MFMA MLP ----
    const int lane = t & 63;
    const int wave = t >> 6;
    const int lr = lane & 15;      // B/C column
    const int lg = lane >> 4;      // k-group / C row-group

    // W1 B-fragments from the pre-packed L2-hot buffer (12 x 16B, no convert)
    bf16x8 bfrag[3][4];
    {
        const bf16x8* bp = (const bf16x8*)Bpack;
#pragma unroll
        for (int ks = 0; ks < 3; ++ks)
#pragma unroll
            for (int n = 0; n < 4; ++n)
                bfrag[ks][n] = bp[(ks * 4 + n) * 64 + lane];
    }
    float w2l[4], b1l[4];
#pragma unroll
    for (int n = 0; n < 4; ++n) {
        w2l[n] = W2[n * 16 + lr];
        b1l[n] = b1g[n * 16 + lr];
    }
    const float b2v = b2g[0];

    const int sbase = blockIdx.x * SPB;
#pragma unroll 1
    for (int mm = 0; mm < 2; ++mm) {
        const int rowb = wave * 32 + mm * 16 + lr;
        bf16x8 a0 = *(const bf16x8*)&Xs[rowb][0 * 32 + lg * 8];
        bf16x8 a1 = *(const bf16x8*)&Xs[rowb][1 * 32 + lg * 8];
        bf16x8 a2 = *(const bf16x8*)&Xs[rowb][2 * 32 + lg * 8];

        f32x4 c0 = {b1l[0], b1l[0], b1l[0], b1l[0]};
        f32x4 c1 = {b1l[1], b1l[1], b1l[1], b1l[1]};
        f32x4 c2 = {b1l[2], b1l[2], b1l[2], b1l[2]};
        f32x4 c3 = {b1l[3], b1l[3], b1l[3], b1l[3]};

        c0 = __builtin_amdgcn_mfma_f32_16x16x32_bf16(a0, bfrag[0][0], c0, 0, 0, 0);
        c1 = __builtin_amdgcn_mfma_f32_16x16x32_bf16(a0, bfrag[0][1], c1, 0, 0, 0);
        c2 = __builtin_amdgcn_mfma_f32_16x16x32_bf16(a0, bfrag[0][2], c2, 0, 0, 0);
        c3 = __builtin_amdgcn_mfma_f32_16x16x32_bf16(a0, bfrag[0][3], c3, 0, 0, 0);
        c0 = __builtin_amdgcn_mfma_f32_16x16x32_bf16(a1, bfrag[1][0], c0, 0, 0, 0);
        c1 = __builtin_amdgcn_mfma_f32_16x16x32_bf16(a1, bfrag[1][1], c1, 0, 0, 0);
        c2 = __builtin_amdgcn_mfma_f32_16x16x32_bf16(a1, bfrag[1][2], c2, 0, 0, 0);
        c3 = __builtin_amdgcn_mfma_f32_16x16x32_bf16(a1, bfrag[1][3], c3, 0, 0, 0);
        c0 = __builtin_amdgcn_mfma_f32_16x16x32_bf16(a2, bfrag[2][0], c0, 0, 0, 0);
        c1 = __builtin_amdgcn_mfma_f32_16x16x32_bf16(a2, bfrag[2][1], c1, 0, 0, 0);
        c2 = __builtin_amdgcn_mfma_f32_16x16x32_bf16(a2, bfrag[2][2], c2, 0, 0, 0);
        c3 = __builtin_amdgcn_mfma_f32_16x16x32_bf16(a2, bfrag[2][3], c3, 0, 0, 0);

        // layer 2: score = relu( sum_j relu(h_j)*W2[j] + b2 )
        float tot[4];
#pragma unroll
        for (int r = 0; r < 4; ++r) {
            float p = fmaxf(c0[r], 0.f) * w2l[0] + fmaxf(c1[r], 0.f) * w2l[1]
                    + fmaxf(c2[r], 0.f) * w2l[2] + fmaxf(c3[r], 0.f) * w2l[3];
            p += __shfl_xor(p, 1);
            p += __shfl_xor(p, 2);
            p += __shfl_xor(p, 4);
            p += __shfl_xor(p, 8);
            tot[r] = p;
        }
        if (lr < 4) {
            int so = sbase + wave * 32 + mm * 16 + lg * 4 + lr;
            if (so < batch) out[batch + so] = fmaxf(tot[lr] + b2v, 0.f);
        }
    }
}

extern "C" void kernel_launch(void* const* d_in, const int* in_sizes, int n_in,
                              void* d_out, int out_size, void* d_ws, size_t ws_size,
                              hipStream_t stream) {
    const int*   uid = (const int*)  d_in[0];
    const int*   iid = (const int*)  d_in[1];
    const float* Uw  = (const float*)d_in[2];
    const float* Qw  = (const float*)d_in[3];
    const float* Aw  = (const float*)d_in[4];
    const float* Bw  = (const float*)d_in[5];
    const float* W1  = (const float*)d_in[6];
    const float* b1  = (const float*)d_in[7];
    const float* W2  = (const float*)d_in[8];
    const float* b2  = (const float*)d_in[9];
    float* out = (float*)d_out;
    unsigned short* Bpack = (unsigned short*)d_ws;   // 12 KB
    int batch = in_sizes[0];

    hipLaunchKernelGGL(prep_pack, dim3(1), dim3(256), 0, stream, W1, Bpack);

    int blocks = (batch + SPB - 1) / SPB;
    hipLaunchKernelGGL(mtn_fused, dim3(blocks), dim3(BLK), 0, stream,
                       uid, iid, Uw, Qw, Aw, Bw, Bpack, b1, W2, b2, out, batch);
}